// Round 9
// baseline (343.589 us; speedup 1.0000x reference)
//
#include <hip/hip_runtime.h>
#include <math.h>

#define NN 100000
#define NE 640000
#define NBLK 98       // ceil(NN / 1024)
#define GBLK 3125     // NN / 32 exactly (32-row tiles)

typedef __bf16 bf16_t;
typedef bf16_t bf16x8 __attribute__((ext_vector_type(8)));
typedef float  f32x4  __attribute__((ext_vector_type(4)));

// ================= CSR build =================

__global__ __launch_bounds__(256) void k_hist(const int* __restrict__ dst,
                                              int* __restrict__ deg) {
    int e = blockIdx.x * 256 + threadIdx.x;
    if (e < NE) atomicAdd(&deg[dst[e]], 1);
}

__global__ __launch_bounds__(1024) void k_bsum(const int* __restrict__ deg,
                                               int* __restrict__ bsum) {
    __shared__ int warr[16];
    int t = threadIdx.x;
    int i = blockIdx.x * 1024 + t;
    int v = (i < NN) ? deg[i] : 0;
    int lane = t & 63, wid = t >> 6;
    #pragma unroll
    for (int off = 32; off > 0; off >>= 1) v += __shfl_xor(v, off, 64);
    if (lane == 0) warr[wid] = v;
    __syncthreads();
    if (t < 16) {
        int s = warr[t];
        #pragma unroll
        for (int off = 8; off > 0; off >>= 1) s += __shfl_xor(s, off, 64);
        if (t == 0) bsum[blockIdx.x] = s;
    }
}

__global__ __launch_bounds__(64) void k_bscan(const int* __restrict__ bsum,
        int* __restrict__ boff, int* __restrict__ rowptr) {
    int lane = threadIdx.x;
    int carry = 0;
    for (int base = 0; base < NBLK; base += 64) {
        int i = base + lane;
        int v = (i < NBLK) ? bsum[i] : 0;
        int s = v;
        #pragma unroll
        for (int off = 1; off < 64; off <<= 1) {
            int u = __shfl_up(s, off, 64);
            if (lane >= off) s += u;
        }
        if (i < NBLK) boff[i] = carry + s - v;
        carry += __shfl(s, 63, 64);
    }
    if (lane == 0) rowptr[NN] = NE;
}

__global__ __launch_bounds__(1024) void k_scan2(const int* __restrict__ deg,
        const int* __restrict__ boff, int* __restrict__ rowptr,
        int* __restrict__ cursor) {
    __shared__ int wsum[16];
    __shared__ int woff[16];
    int t = threadIdx.x;
    int lane = t & 63, wid = t >> 6;
    int i = blockIdx.x * 1024 + t;
    int v = (i < NN) ? deg[i] : 0;
    int s = v;
    #pragma unroll
    for (int off = 1; off < 64; off <<= 1) {
        int u = __shfl_up(s, off, 64);
        if (lane >= off) s += u;
    }
    if (lane == 63) wsum[wid] = s;
    __syncthreads();
    if (wid == 0) {
        int ws = (lane < 16) ? wsum[lane] : 0;
        #pragma unroll
        for (int off = 1; off < 16; off <<= 1) {
            int u = __shfl_up(ws, off, 64);
            if (lane >= off) ws += u;
        }
        if (lane < 16) woff[lane] = ws;
    }
    __syncthreads();
    if (i < NN) {
        int excl = boff[blockIdx.x] + (s - v) + (wid ? woff[wid - 1] : 0);
        rowptr[i] = excl;
        cursor[i] = excl;
    }
}

__global__ __launch_bounds__(256) void k_fill(const int* __restrict__ src,
        const int* __restrict__ dst, int* __restrict__ cursor,
        int* __restrict__ csr) {
    int e = blockIdx.x * 256 + threadIdx.x;
    if (e >= NE) return;
    int p = atomicAdd(&cursor[dst[e]], 1);
    csr[p] = src[e];
}

// ========== weight split (f32 -> hi/lo bf16) in MFMA B-fragment order ==========
// Wf[((ct*8 + it)*64 + lane)*8 + j] = W[col = ct*16 + (lane&15)]
//                                      [k   = it*32 + (lane>>4)*8 + j]

__global__ __launch_bounds__(256) void k_split_w(const float* __restrict__ W1l,
        const float* __restrict__ W1r, const float* __restrict__ W2l,
        const float* __restrict__ W2r, bf16_t* __restrict__ W1fh,
        bf16_t* __restrict__ W1fl, bf16_t* __restrict__ W2fh,
        bf16_t* __restrict__ W2fl) {
    int b = blockIdx.x, t = threadIdx.x;
    float f;
    bf16_t* Wfh;
    bf16_t* Wfl;
    int j;
    if (b < 256) {        // W1cat[j] = [W1l[j,:] | W1r[j,:]]
        j = b;
        f = (t < 128) ? W1l[j * 128 + t] : W1r[j * 128 + (t - 128)];
        Wfh = W1fh; Wfl = W1fl;
    } else {              // W2cat rows 0..127 = W2l, 128..255 = W2r
        j = b - 256;
        f = (j < 128) ? W2l[j * 256 + t] : W2r[(j - 128) * 256 + t];
        Wfh = W2fh; Wfl = W2fl;
    }
    bf16_t h = (bf16_t)f;
    bf16_t l = (bf16_t)(f - (float)h);
    int idx = (((j >> 4) * 8 + (t >> 5)) * 64 + ((t >> 3) & 3) * 16 + (j & 15)) * 8 + (t & 7);
    Wfh[idx] = h;
    Wfl[idx] = l;
}

// ============ FUSED gather + layer-1 + layer-2 GEMM, 32-row tiles =============
// R19 structure (132us) + R21: s_setprio(1) around the ds_read+MFMA clusters
// (T5; 4 blocks/CU at different phases -> scheduler favors MFMA waves over
// gather/W-issuing waves of neighbor blocks).
// Frag-order index for element [r][c]: (((r>>4)*8+(c>>5))*64+((c>>3)&3)*16+(r&15))*8+(c&7)
// Reader lane reads &s[((mt*8+it)*64+lane)*8] -> 16 contiguous B/lane, 1KB/wave.

__device__ __forceinline__ void splitv(float4 v0, float4 v1,
                                       bf16x8& h, bf16x8& l) {
    float f[8] = {v0.x, v0.y, v0.z, v0.w, v1.x, v1.y, v1.z, v1.w};
    #pragma unroll
    for (int i = 0; i < 8; i++) {
        bf16_t hi = (bf16_t)f[i];
        h[i] = hi;
        l[i] = (bf16_t)(f[i] - (float)hi);
    }
}

__device__ __forceinline__ void split2(f32x4 a, f32x4 b,
                                       bf16x8& h, bf16x8& l) {
    #pragma unroll
    for (int i = 0; i < 4; i++) {
        bf16_t hi = (bf16_t)a[i];
        h[i] = hi; l[i] = (bf16_t)(a[i] - (float)hi);
    }
    #pragma unroll
    for (int i = 0; i < 4; i++) {
        bf16_t hi = (bf16_t)b[i];
        h[i + 4] = hi; l[i + 4] = (bf16_t)(b[i] - (float)hi);
    }
}

__global__ __launch_bounds__(256, 4) void k_gemm_fused(const float* __restrict__ Ax,
        const int* __restrict__ rowptr, const int* __restrict__ csr,
        const bf16_t* __restrict__ W1fh, const bf16_t* __restrict__ W1fl,
        const bf16_t* __restrict__ W2fh, const bf16_t* __restrict__ W2fl,
        const float* __restrict__ bias,
        float* __restrict__ C2a, float* __restrict__ C2r) {
    __shared__ bf16_t sHf[32 * 256], sLf[32 * 256];  // A frags, then h1 frags (16KB each)
    __shared__ float pr[32][4];
    int t = threadIdx.x;
    int wave = t >> 6, lane = t & 63, quad = lane >> 4, l16 = lane & 15;
    int r0 = blockIdx.x * 32;
    // ---------- prologue B: own-row x for k 128..255 (threads 0..127) ----------
    if (t < 128) {
        int arow = t >> 2, aseg = t & 3;             // 8 f32 per thread per it
        int grow = r0 + arow;
        #pragma unroll
        for (int it = 4; it < 8; it++) {
            const float* p = &Ax[(size_t)grow * 128 + (it - 4) * 32 + aseg * 8];
            bf16x8 h8, l8;
            splitv(*(const float4*)p, *(const float4*)(p + 4), h8, l8);
            int idx = (((arow >> 4) * 8 + it) * 64 + aseg * 16 + (arow & 15)) * 8;
            *(bf16x8*)&sHf[idx] = h8;
            *(bf16x8*)&sLf[idx] = l8;
        }
    }
    // ---------- prologue A: gather-mean of x[neighbors] for k 0..127 ----------
    // 8 threads/node (seg 0..7), 32 nodes; each thread owns 16 cols = seg*16..+15.
    {
        int node = t >> 3, seg = t & 7;
        int gn = r0 + node;
        int beg = rowptr[gn], end = rowptr[gn + 1];
        int c0 = seg << 4;
        f32x4 a0 = {}, a1 = {}, a2 = {}, a3 = {};
        int e = beg;
        for (; e + 1 < end; e += 2) {
            int s0 = csr[e], s1 = csr[e + 1];
            const float* p0 = Ax + (size_t)s0 * 128 + c0;
            const float* p1 = Ax + (size_t)s1 * 128 + c0;
            a0 += *(const f32x4*)(p0);      a0 += *(const f32x4*)(p1);
            a1 += *(const f32x4*)(p0 + 4);  a1 += *(const f32x4*)(p1 + 4);
            a2 += *(const f32x4*)(p0 + 8);  a2 += *(const f32x4*)(p1 + 8);
            a3 += *(const f32x4*)(p0 + 12); a3 += *(const f32x4*)(p1 + 12);
        }
        if (e < end) {
            const float* p0 = Ax + (size_t)csr[e] * 128 + c0;
            a0 += *(const f32x4*)(p0);
            a1 += *(const f32x4*)(p0 + 4);
            a2 += *(const f32x4*)(p0 + 8);
            a3 += *(const f32x4*)(p0 + 12);
        }
        float iv = 1.0f / (float)max(end - beg, 1);
        a0 *= iv; a1 *= iv; a2 *= iv; a3 *= iv;
        // k = it*32 + (seg&1)*16 + j, it = seg>>1; (k>>3)&3 = (seg&1)*2 + (j>>3)
        int it = seg >> 1, half = seg & 1;
        bf16x8 h8, l8;
        split2(a0, a1, h8, l8);
        int idx = (((node >> 4) * 8 + it) * 64 + (half * 2 + 0) * 16 + (node & 15)) * 8;
        *(bf16x8*)&sHf[idx] = h8;
        *(bf16x8*)&sLf[idx] = l8;
        split2(a2, a3, h8, l8);
        idx = (((node >> 4) * 8 + it) * 64 + (half * 2 + 1) * 16 + (node & 15)) * 8;
        *(bf16x8*)&sHf[idx] = h8;
        *(bf16x8*)&sLf[idx] = l8;
    }
    __syncthreads();
    // ---------- phase 1 K-loop: no barriers, no staging ----------
    f32x4 acc[2][4] = {};
    for (int it = 0; it < 8; it++) {
        bf16x8 bh[4], bl[4];
        #pragma unroll
        for (int nt = 0; nt < 4; nt++) {
            size_t fo = (size_t)(((wave * 4 + nt) * 8 + it) * 64 + lane) * 8;
            bh[nt] = *(const bf16x8*)&W1fh[fo];
            bl[nt] = *(const bf16x8*)&W1fl[fo];
        }
        __builtin_amdgcn_s_setprio(1);
        #pragma unroll
        for (int mt = 0; mt < 2; mt++) {
            int fb = ((mt * 8 + it) * 64 + lane) * 8;
            bf16x8 ah = *(bf16x8*)&sHf[fb];
            bf16x8 al = *(bf16x8*)&sLf[fb];
            #pragma unroll
            for (int nt = 0; nt < 4; nt++) {
                acc[mt][nt] = __builtin_amdgcn_mfma_f32_16x16x32_bf16(ah, bh[nt], acc[mt][nt], 0, 0, 0);
                acc[mt][nt] = __builtin_amdgcn_mfma_f32_16x16x32_bf16(al, bh[nt], acc[mt][nt], 0, 0, 0);
                acc[mt][nt] = __builtin_amdgcn_mfma_f32_16x16x32_bf16(ah, bl[nt], acc[mt][nt], 0, 0, 0);
            }
        }
        __builtin_amdgcn_s_setprio(0);
    }
    // ---------- epilogue 1: bias + row L2-norm + relu ----------
    float bcol[4];
    #pragma unroll
    for (int nt = 0; nt < 4; nt++) bcol[nt] = bias[wave * 64 + nt * 16 + l16];
    #pragma unroll
    for (int mt = 0; mt < 2; mt++)
        #pragma unroll
        for (int nt = 0; nt < 4; nt++)
            #pragma unroll
            for (int rg = 0; rg < 4; rg++)
                acc[mt][nt][rg] += bcol[nt];
    float ss[2][4];
    #pragma unroll
    for (int mt = 0; mt < 2; mt++)
        #pragma unroll
        for (int rg = 0; rg < 4; rg++) {
            float s = 0.f;
            #pragma unroll
            for (int nt = 0; nt < 4; nt++) s += acc[mt][nt][rg] * acc[mt][nt][rg];
            #pragma unroll
            for (int off = 1; off < 16; off <<= 1) s += __shfl_xor(s, off, 64);
            ss[mt][rg] = s;
        }
    if (l16 == 0) {
        #pragma unroll
        for (int mt = 0; mt < 2; mt++)
            #pragma unroll
            for (int rg = 0; rg < 4; rg++)
                pr[mt * 16 + quad * 4 + rg][wave] = ss[mt][rg];
    }
    __syncthreads();   // all phase-1 LDS reads done; pr visible
    // ---------- h1 tile -> LDS (fragment order, hi/lo), overwriting A ----------
    #pragma unroll
    for (int mt = 0; mt < 2; mt++)
        #pragma unroll
        for (int rg = 0; rg < 4; rg++) {
            int r = mt * 16 + quad * 4 + rg;
            float tot = pr[r][0] + pr[r][1] + pr[r][2] + pr[r][3];
            float inv = 1.0f / fmaxf(sqrtf(tot), 1e-12f);
            #pragma unroll
            for (int nt = 0; nt < 4; nt++) {
                int c = wave * 64 + nt * 16 + l16;
                float v = fmaxf(acc[mt][nt][rg] * inv, 0.f);
                bf16_t h = (bf16_t)v;
                bf16_t l = (bf16_t)(v - (float)h);
                int idx = (((r >> 4) * 8 + (c >> 5)) * 64 + ((c >> 3) & 3) * 16 + (r & 15)) * 8 + (c & 7);
                sHf[idx] = h;
                sLf[idx] = l;
            }
        }
    __syncthreads();
    // ---------- phase 2 K-loop: no barriers, no staging ----------
    f32x4 acc2[2][4] = {};
    for (int it = 0; it < 8; it++) {
        bf16x8 bh[4], bl[4];
        #pragma unroll
        for (int nt = 0; nt < 4; nt++) {
            size_t fo = (size_t)(((wave * 4 + nt) * 8 + it) * 64 + lane) * 8;
            bh[nt] = *(const bf16x8*)&W2fh[fo];
            bl[nt] = *(const bf16x8*)&W2fl[fo];
        }
        __builtin_amdgcn_s_setprio(1);
        #pragma unroll
        for (int mt = 0; mt < 2; mt++) {
            int fb = ((mt * 8 + it) * 64 + lane) * 8;
            bf16x8 ah = *(bf16x8*)&sHf[fb];
            bf16x8 al = *(bf16x8*)&sLf[fb];
            #pragma unroll
            for (int nt = 0; nt < 4; nt++) {
                acc2[mt][nt] = __builtin_amdgcn_mfma_f32_16x16x32_bf16(ah, bh[nt], acc2[mt][nt], 0, 0, 0);
                acc2[mt][nt] = __builtin_amdgcn_mfma_f32_16x16x32_bf16(al, bh[nt], acc2[mt][nt], 0, 0, 0);
                acc2[mt][nt] = __builtin_amdgcn_mfma_f32_16x16x32_bf16(ah, bl[nt], acc2[mt][nt], 0, 0, 0);
            }
        }
        __builtin_amdgcn_s_setprio(0);
    }
    // ---------- C-write: cols 0..127 -> C2a (gathered), 128..255 -> C2r ----------
    float* dstb = (wave < 2) ? C2a : C2r;
    int cb = (wave < 2) ? (wave * 64) : ((wave - 2) * 64);
    #pragma unroll
    for (int mt = 0; mt < 2; mt++)
        #pragma unroll
        for (int rg = 0; rg < 4; rg++) {
            int row = r0 + mt * 16 + quad * 4 + rg;
            #pragma unroll
            for (int nt = 0; nt < 4; nt++) {
                int col = cb + nt * 16 + l16;
                dstb[(size_t)row * 128 + col] = acc2[mt][nt][rg];
            }
        }
}

// ==== fused layer-2 tail: gather-mean p2 (C2a) + combine (C2r) + norm +
//      BOTH layer-3 per-node dots (q3 = W3l.h2, a3 = W3r.h2). h2 never
//      materialized. R21: 4-edge unroll, 4 independent accumulator chains.

__global__ __launch_bounds__(256) void k_gather_combine(const float* __restrict__ C2a,
        const float* __restrict__ C2r,
        const int* __restrict__ rowptr, const int* __restrict__ csr,
        const float* __restrict__ b2, const float* __restrict__ W3l,
        const float* __restrict__ W3r,
        float* __restrict__ q3, float* __restrict__ a3) {
    __shared__ float sw[512];              // 0..255 = W3l, 256..511 = W3r
    int t = threadIdx.x;
    sw[t] = W3l[t];
    sw[256 + t] = W3r[t];
    __syncthreads();
    int tid = blockIdx.x * 256 + t;
    int node = tid >> 5;
    if (node >= NN) return;
    int l = tid & 31;
    int lane4 = l << 2;
    int beg = rowptr[node], end = rowptr[node + 1];
    f32x4 ac0 = {}, ac1 = {}, ac2 = {}, ac3 = {};
    int e = beg;
    for (; e + 3 < end; e += 4) {
        int s0 = csr[e], s1 = csr[e + 1], s2 = csr[e + 2], s3 = csr[e + 3];
        ac0 += *(const f32x4*)(C2a + (size_t)s0 * 128 + lane4);
        ac1 += *(const f32x4*)(C2a + (size_t)s1 * 128 + lane4);
        ac2 += *(const f32x4*)(C2a + (size_t)s2 * 128 + lane4);
        ac3 += *(const f32x4*)(C2a + (size_t)s3 * 128 + lane4);
    }
    if (e + 1 < end) {
        int s0 = csr[e], s1 = csr[e + 1];
        ac0 += *(const f32x4*)(C2a + (size_t)s0 * 128 + lane4);
        ac1 += *(const f32x4*)(C2a + (size_t)s1 * 128 + lane4);
        e += 2;
    }
    if (e < end) {
        ac2 += *(const f32x4*)(C2a + (size_t)csr[e] * 128 + lane4);
    }
    f32x4 acc = (ac0 + ac1) + (ac2 + ac3);
    float iv = 1.0f / (float)max(end - beg, 1);
    float4 r = *(const float4*)&C2r[(size_t)node * 128 + lane4];
    float4 b = *(const float4*)&b2[lane4];
    float v0 = acc[0] * iv + r.x + b.x;
    float v1 = acc[1] * iv + r.y + b.y;
    float v2 = acc[2] * iv + r.z + b.z;
    float v3 = acc[3] * iv + r.w + b.w;
    float s = v0 * v0 + v1 * v1 + v2 * v2 + v3 * v3;
    #pragma unroll
    for (int off = 16; off > 0; off >>= 1) s += __shfl_xor(s, off, 64);
    float invn = 1.0f / fmaxf(sqrtf(s), 1e-12f);
    float4 o;
    o.x = fmaxf(v0 * invn, 0.f); o.y = fmaxf(v1 * invn, 0.f);
    o.z = fmaxf(v2 * invn, 0.f); o.w = fmaxf(v3 * invn, 0.f);
    float q0 = o.x * sw[lane4] + o.y * sw[lane4+1] + o.z * sw[lane4+2] + o.w * sw[lane4+3];
    float q1 = o.x * sw[128+lane4] + o.y * sw[129+lane4] + o.z * sw[130+lane4] + o.w * sw[131+lane4];
    float c0 = o.x * sw[256+lane4] + o.y * sw[257+lane4] + o.z * sw[258+lane4] + o.w * sw[259+lane4];
    float c1 = o.x * sw[384+lane4] + o.y * sw[385+lane4] + o.z * sw[386+lane4] + o.w * sw[387+lane4];
    #pragma unroll
    for (int off = 16; off > 0; off >>= 1) {
        q0 += __shfl_xor(q0, off, 64);
        q1 += __shfl_xor(q1, off, 64);
        c0 += __shfl_xor(c0, off, 64);
        c1 += __shfl_xor(c1, off, 64);
    }
    if (l == 0) {
        q3[2 * node] = q0;
        q3[2 * node + 1] = q1;
        a3[2 * node] = c0;
        a3[2 * node + 1] = c1;
    }
}

// ============ final: tiny q3 gather + a3 + norm + log_softmax ============

__global__ __launch_bounds__(256) void k_final(const float* __restrict__ a3,
        const float* __restrict__ b3, const float* __restrict__ q3,
        const int* __restrict__ rowptr, const int* __restrict__ csr,
        float* __restrict__ out) {
    int i = blockIdx.x * 256 + threadIdx.x;
    if (i >= NN) return;
    int beg = rowptr[i], end = rowptr[i + 1];
    float g0 = 0.f, g1 = 0.f;
    for (int e = beg; e < end; e++) {
        int s = csr[e];
        g0 += q3[2 * s];
        g1 += q3[2 * s + 1];
    }
    float ivd = 1.0f / (float)max(end - beg, 1);
    float v0 = g0 * ivd + a3[2 * i] + b3[0];
    float v1 = g1 * ivd + a3[2 * i + 1] + b3[1];
    float invn = 1.0f / fmaxf(sqrtf(v0 * v0 + v1 * v1), 1e-12f);
    v0 *= invn; v1 *= invn;
    float mx = fmaxf(v0, v1);
    float l = logf(expf(v0 - mx) + expf(v1 - mx));
    out[2 * i] = v0 - mx - l;
    out[2 * i + 1] = v1 - mx - l;
}

// ================= launch =================

extern "C" void kernel_launch(void* const* d_in, const int* in_sizes, int n_in,
                              void* d_out, int out_size, void* d_ws, size_t ws_size,
                              hipStream_t stream) {
    const float* x   = (const float*)d_in[0];
    const int*   ei  = (const int*)d_in[1];
    const float* W1l = (const float*)d_in[2];
    const float* W1r = (const float*)d_in[3];
    const float* b1  = (const float*)d_in[4];
    const float* W2l = (const float*)d_in[5];
    const float* W2r = (const float*)d_in[6];
    const float* b2  = (const float*)d_in[7];
    const float* W3l = (const float*)d_in[8];
    const float* W3r = (const float*)d_in[9];
    const float* b3  = (const float*)d_in[10];
    float* out = (float*)d_out;
    const int* src = ei;
    const int* dst = ei + NE;

    // ---- workspace layout ----
    int* deg    = (int*)d_ws;                     // 102400
    int* rowptr = deg + 102400;
    int* cursor = rowptr + 102400;
    int* csr    = cursor + 102400;                // 655360
    int* bsum   = csr + 655360;                   // 128
    int* boff   = bsum + 128;                     // 128
    bf16_t* W1h  = (bf16_t*)(boff + 128);         // 65536 bf16 each (frag order)
    bf16_t* W1lo = W1h + 65536;
    bf16_t* W2h  = W1lo + 65536;
    bf16_t* W2lo = W2h + 65536;
    float* C2a  = (float*)(W2lo + 65536);         // NN*128 f32 (51.2MB, gathered)
    float* C2r  = C2a + (size_t)NN * 128;         // NN*128 f32 (own-row)
    float* q3   = C2r + (size_t)NN * 128;         // 200000
    float* a3   = q3 + 200000;                    // 200000

    // ---- CSR build (multi-block scan) ----
    hipMemsetAsync(deg, 0, NN * sizeof(int), stream);
    k_hist<<<(NE + 255) / 256, 256, 0, stream>>>(dst, deg);
    k_bsum<<<NBLK, 1024, 0, stream>>>(deg, bsum);
    k_bscan<<<1, 64, 0, stream>>>(bsum, boff, rowptr);
    k_scan2<<<NBLK, 1024, 0, stream>>>(deg, boff, rowptr, cursor);
    k_fill<<<(NE + 255) / 256, 256, 0, stream>>>(src, dst, cursor, csr);

    // ---- weight split (fragment order, both layers in one kernel) ----
    k_split_w<<<512, 256, 0, stream>>>(W1l, W1r, W2l, W2r, W1h, W1lo, W2h, W2lo);

    // ---- fused gather + layer-1 + layer-2 GEMM (h1 never leaves LDS) ----
    k_gemm_fused<<<GBLK, 256, 0, stream>>>(x, rowptr, csr, W1h, W1lo, W2h, W2lo, b1, C2a, C2r);

    // ---- layer-2 tail (gather+combine+q3+a3 fused; h2 eliminated) ----
    k_gather_combine<<<(NN * 32 + 255) / 256, 256, 0, stream>>>(C2a, C2r, rowptr, csr, b2, W3l, W3r, q3, a3);

    // ---- layer 3 (tiny q3 gather) ----
    k_final<<<(NN + 255) / 256, 256, 0, stream>>>(a3, b3, q3, rowptr, csr, out);
}

// Round 10
// 340.722 us; speedup vs baseline: 1.0084x; 1.0084x over previous
//
#include <hip/hip_runtime.h>
#include <math.h>

#define NN 100000
#define NE 640000
#define NBLK 98       // ceil(NN / 1024)
#define GBLK 3125     // NN / 32 exactly (32-row tiles)

typedef __bf16 bf16_t;
typedef bf16_t bf16x8 __attribute__((ext_vector_type(8)));
typedef float  f32x4  __attribute__((ext_vector_type(4)));

// ================= CSR build =================

__global__ __launch_bounds__(256) void k_hist(const int* __restrict__ dst,
                                              int* __restrict__ deg) {
    int e = blockIdx.x * 256 + threadIdx.x;
    if (e < NE) atomicAdd(&deg[dst[e]], 1);
}

__global__ __launch_bounds__(1024) void k_bsum(const int* __restrict__ deg,
                                               int* __restrict__ bsum) {
    __shared__ int warr[16];
    int t = threadIdx.x;
    int i = blockIdx.x * 1024 + t;
    int v = (i < NN) ? deg[i] : 0;
    int lane = t & 63, wid = t >> 6;
    #pragma unroll
    for (int off = 32; off > 0; off >>= 1) v += __shfl_xor(v, off, 64);
    if (lane == 0) warr[wid] = v;
    __syncthreads();
    if (t < 16) {
        int s = warr[t];
        #pragma unroll
        for (int off = 8; off > 0; off >>= 1) s += __shfl_xor(s, off, 64);
        if (t == 0) bsum[blockIdx.x] = s;
    }
}

__global__ __launch_bounds__(64) void k_bscan(const int* __restrict__ bsum,
        int* __restrict__ boff, int* __restrict__ rowptr) {
    int lane = threadIdx.x;
    int carry = 0;
    for (int base = 0; base < NBLK; base += 64) {
        int i = base + lane;
        int v = (i < NBLK) ? bsum[i] : 0;
        int s = v;
        #pragma unroll
        for (int off = 1; off < 64; off <<= 1) {
            int u = __shfl_up(s, off, 64);
            if (lane >= off) s += u;
        }
        if (i < NBLK) boff[i] = carry + s - v;
        carry += __shfl(s, 63, 64);
    }
    if (lane == 0) rowptr[NN] = NE;
}

__global__ __launch_bounds__(1024) void k_scan2(const int* __restrict__ deg,
        const int* __restrict__ boff, int* __restrict__ rowptr,
        int* __restrict__ cursor) {
    __shared__ int wsum[16];
    __shared__ int woff[16];
    int t = threadIdx.x;
    int lane = t & 63, wid = t >> 6;
    int i = blockIdx.x * 1024 + t;
    int v = (i < NN) ? deg[i] : 0;
    int s = v;
    #pragma unroll
    for (int off = 1; off < 64; off <<= 1) {
        int u = __shfl_up(s, off, 64);
        if (lane >= off) s += u;
    }
    if (lane == 63) wsum[wid] = s;
    __syncthreads();
    if (wid == 0) {
        int ws = (lane < 16) ? wsum[lane] : 0;
        #pragma unroll
        for (int off = 1; off < 16; off <<= 1) {
            int u = __shfl_up(ws, off, 64);
            if (lane >= off) ws += u;
        }
        if (lane < 16) woff[lane] = ws;
    }
    __syncthreads();
    if (i < NN) {
        int excl = boff[blockIdx.x] + (s - v) + (wid ? woff[wid - 1] : 0);
        rowptr[i] = excl;
        cursor[i] = excl;
    }
}

__global__ __launch_bounds__(256) void k_fill(const int* __restrict__ src,
        const int* __restrict__ dst, int* __restrict__ cursor,
        int* __restrict__ csr) {
    int e = blockIdx.x * 256 + threadIdx.x;
    if (e >= NE) return;
    int p = atomicAdd(&cursor[dst[e]], 1);
    csr[p] = src[e];
}

// ========== weight split (f32 -> hi/lo bf16) in MFMA B-fragment order ==========
// Wf[((ct*8 + it)*64 + lane)*8 + j] = W[col = ct*16 + (lane&15)]
//                                      [k   = it*32 + (lane>>4)*8 + j]

__global__ __launch_bounds__(256) void k_split_w(const float* __restrict__ W1l,
        const float* __restrict__ W1r, const float* __restrict__ W2l,
        const float* __restrict__ W2r, bf16_t* __restrict__ W1fh,
        bf16_t* __restrict__ W1fl, bf16_t* __restrict__ W2fh,
        bf16_t* __restrict__ W2fl) {
    int b = blockIdx.x, t = threadIdx.x;
    float f;
    bf16_t* Wfh;
    bf16_t* Wfl;
    int j;
    if (b < 256) {        // W1cat[j] = [W1l[j,:] | W1r[j,:]]
        j = b;
        f = (t < 128) ? W1l[j * 128 + t] : W1r[j * 128 + (t - 128)];
        Wfh = W1fh; Wfl = W1fl;
    } else {              // W2cat rows 0..127 = W2l, 128..255 = W2r
        j = b - 256;
        f = (j < 128) ? W2l[j * 256 + t] : W2r[(j - 128) * 256 + t];
        Wfh = W2fh; Wfl = W2fl;
    }
    bf16_t h = (bf16_t)f;
    bf16_t l = (bf16_t)(f - (float)h);
    int idx = (((j >> 4) * 8 + (t >> 5)) * 64 + ((t >> 3) & 3) * 16 + (j & 15)) * 8 + (t & 7);
    Wfh[idx] = h;
    Wfl[idx] = l;
}

// ============ FUSED gather + layer-1 + layer-2 GEMM, 32-row tiles =============
// R19 structure (129us best). R22: setprio REVERTED (R21: -3us, no wave role
// diversity to arbitrate). NEW: C2a/C2r writes are NON-TEMPORAL -- they are
// write-once, consumed by the next kernel; streaming 100MB through L2 was
// evicting the x rows that the random gather re-reads ~6.4x (FETCH 182MB vs
// 51MB compulsory = L2-miss amplification).
// Frag-order index for element [r][c]: (((r>>4)*8+(c>>5))*64+((c>>3)&3)*16+(r&15))*8+(c&7)
// Reader lane reads &s[((mt*8+it)*64+lane)*8] -> 16 contiguous B/lane, 1KB/wave.

__device__ __forceinline__ void splitv(float4 v0, float4 v1,
                                       bf16x8& h, bf16x8& l) {
    float f[8] = {v0.x, v0.y, v0.z, v0.w, v1.x, v1.y, v1.z, v1.w};
    #pragma unroll
    for (int i = 0; i < 8; i++) {
        bf16_t hi = (bf16_t)f[i];
        h[i] = hi;
        l[i] = (bf16_t)(f[i] - (float)hi);
    }
}

__device__ __forceinline__ void split2(f32x4 a, f32x4 b,
                                       bf16x8& h, bf16x8& l) {
    #pragma unroll
    for (int i = 0; i < 4; i++) {
        bf16_t hi = (bf16_t)a[i];
        h[i] = hi; l[i] = (bf16_t)(a[i] - (float)hi);
    }
    #pragma unroll
    for (int i = 0; i < 4; i++) {
        bf16_t hi = (bf16_t)b[i];
        h[i + 4] = hi; l[i + 4] = (bf16_t)(b[i] - (float)hi);
    }
}

__global__ __launch_bounds__(256, 4) void k_gemm_fused(const float* __restrict__ Ax,
        const int* __restrict__ rowptr, const int* __restrict__ csr,
        const bf16_t* __restrict__ W1fh, const bf16_t* __restrict__ W1fl,
        const bf16_t* __restrict__ W2fh, const bf16_t* __restrict__ W2fl,
        const float* __restrict__ bias,
        float* __restrict__ C2a, float* __restrict__ C2r) {
    __shared__ bf16_t sHf[32 * 256], sLf[32 * 256];  // A frags, then h1 frags (16KB each)
    __shared__ float pr[32][4];
    int t = threadIdx.x;
    int wave = t >> 6, lane = t & 63, quad = lane >> 4, l16 = lane & 15;
    int r0 = blockIdx.x * 32;
    // ---------- prologue B: own-row x for k 128..255 (threads 0..127) ----------
    if (t < 128) {
        int arow = t >> 2, aseg = t & 3;             // 8 f32 per thread per it
        int grow = r0 + arow;
        #pragma unroll
        for (int it = 4; it < 8; it++) {
            const float* p = &Ax[(size_t)grow * 128 + (it - 4) * 32 + aseg * 8];
            bf16x8 h8, l8;
            splitv(*(const float4*)p, *(const float4*)(p + 4), h8, l8);
            int idx = (((arow >> 4) * 8 + it) * 64 + aseg * 16 + (arow & 15)) * 8;
            *(bf16x8*)&sHf[idx] = h8;
            *(bf16x8*)&sLf[idx] = l8;
        }
    }
    // ---------- prologue A: gather-mean of x[neighbors] for k 0..127 ----------
    // 8 threads/node (seg 0..7), 32 nodes; each thread owns 16 cols = seg*16..+15.
    {
        int node = t >> 3, seg = t & 7;
        int gn = r0 + node;
        int beg = rowptr[gn], end = rowptr[gn + 1];
        int c0 = seg << 4;
        f32x4 a0 = {}, a1 = {}, a2 = {}, a3 = {};
        int e = beg;
        for (; e + 1 < end; e += 2) {
            int s0 = csr[e], s1 = csr[e + 1];
            const float* p0 = Ax + (size_t)s0 * 128 + c0;
            const float* p1 = Ax + (size_t)s1 * 128 + c0;
            a0 += *(const f32x4*)(p0);      a0 += *(const f32x4*)(p1);
            a1 += *(const f32x4*)(p0 + 4);  a1 += *(const f32x4*)(p1 + 4);
            a2 += *(const f32x4*)(p0 + 8);  a2 += *(const f32x4*)(p1 + 8);
            a3 += *(const f32x4*)(p0 + 12); a3 += *(const f32x4*)(p1 + 12);
        }
        if (e < end) {
            const float* p0 = Ax + (size_t)csr[e] * 128 + c0;
            a0 += *(const f32x4*)(p0);
            a1 += *(const f32x4*)(p0 + 4);
            a2 += *(const f32x4*)(p0 + 8);
            a3 += *(const f32x4*)(p0 + 12);
        }
        float iv = 1.0f / (float)max(end - beg, 1);
        a0 *= iv; a1 *= iv; a2 *= iv; a3 *= iv;
        // k = it*32 + (seg&1)*16 + j, it = seg>>1; (k>>3)&3 = (seg&1)*2 + (j>>3)
        int it = seg >> 1, half = seg & 1;
        bf16x8 h8, l8;
        split2(a0, a1, h8, l8);
        int idx = (((node >> 4) * 8 + it) * 64 + (half * 2 + 0) * 16 + (node & 15)) * 8;
        *(bf16x8*)&sHf[idx] = h8;
        *(bf16x8*)&sLf[idx] = l8;
        split2(a2, a3, h8, l8);
        idx = (((node >> 4) * 8 + it) * 64 + (half * 2 + 1) * 16 + (node & 15)) * 8;
        *(bf16x8*)&sHf[idx] = h8;
        *(bf16x8*)&sLf[idx] = l8;
    }
    __syncthreads();
    // ---------- phase 1 K-loop: no barriers, no staging ----------
    f32x4 acc[2][4] = {};
    for (int it = 0; it < 8; it++) {
        bf16x8 bh[4], bl[4];
        #pragma unroll
        for (int nt = 0; nt < 4; nt++) {
            size_t fo = (size_t)(((wave * 4 + nt) * 8 + it) * 64 + lane) * 8;
            bh[nt] = *(const bf16x8*)&W1fh[fo];
            bl[nt] = *(const bf16x8*)&W1fl[fo];
        }
        #pragma unroll
        for (int mt = 0; mt < 2; mt++) {
            int fb = ((mt * 8 + it) * 64 + lane) * 8;
            bf16x8 ah = *(bf16x8*)&sHf[fb];
            bf16x8 al = *(bf16x8*)&sLf[fb];
            #pragma unroll
            for (int nt = 0; nt < 4; nt++) {
                acc[mt][nt] = __builtin_amdgcn_mfma_f32_16x16x32_bf16(ah, bh[nt], acc[mt][nt], 0, 0, 0);
                acc[mt][nt] = __builtin_amdgcn_mfma_f32_16x16x32_bf16(al, bh[nt], acc[mt][nt], 0, 0, 0);
                acc[mt][nt] = __builtin_amdgcn_mfma_f32_16x16x32_bf16(ah, bl[nt], acc[mt][nt], 0, 0, 0);
            }
        }
    }
    // ---------- epilogue 1: bias + row L2-norm + relu ----------
    float bcol[4];
    #pragma unroll
    for (int nt = 0; nt < 4; nt++) bcol[nt] = bias[wave * 64 + nt * 16 + l16];
    #pragma unroll
    for (int mt = 0; mt < 2; mt++)
        #pragma unroll
        for (int nt = 0; nt < 4; nt++)
            #pragma unroll
            for (int rg = 0; rg < 4; rg++)
                acc[mt][nt][rg] += bcol[nt];
    float ss[2][4];
    #pragma unroll
    for (int mt = 0; mt < 2; mt++)
        #pragma unroll
        for (int rg = 0; rg < 4; rg++) {
            float s = 0.f;
            #pragma unroll
            for (int nt = 0; nt < 4; nt++) s += acc[mt][nt][rg] * acc[mt][nt][rg];
            #pragma unroll
            for (int off = 1; off < 16; off <<= 1) s += __shfl_xor(s, off, 64);
            ss[mt][rg] = s;
        }
    if (l16 == 0) {
        #pragma unroll
        for (int mt = 0; mt < 2; mt++)
            #pragma unroll
            for (int rg = 0; rg < 4; rg++)
                pr[mt * 16 + quad * 4 + rg][wave] = ss[mt][rg];
    }
    __syncthreads();   // all phase-1 LDS reads done; pr visible
    // ---------- h1 tile -> LDS (fragment order, hi/lo), overwriting A ----------
    #pragma unroll
    for (int mt = 0; mt < 2; mt++)
        #pragma unroll
        for (int rg = 0; rg < 4; rg++) {
            int r = mt * 16 + quad * 4 + rg;
            float tot = pr[r][0] + pr[r][1] + pr[r][2] + pr[r][3];
            float inv = 1.0f / fmaxf(sqrtf(tot), 1e-12f);
            #pragma unroll
            for (int nt = 0; nt < 4; nt++) {
                int c = wave * 64 + nt * 16 + l16;
                float v = fmaxf(acc[mt][nt][rg] * inv, 0.f);
                bf16_t h = (bf16_t)v;
                bf16_t l = (bf16_t)(v - (float)h);
                int idx = (((r >> 4) * 8 + (c >> 5)) * 64 + ((c >> 3) & 3) * 16 + (r & 15)) * 8 + (c & 7);
                sHf[idx] = h;
                sLf[idx] = l;
            }
        }
    __syncthreads();
    // ---------- phase 2 K-loop: no barriers, no staging ----------
    f32x4 acc2[2][4] = {};
    for (int it = 0; it < 8; it++) {
        bf16x8 bh[4], bl[4];
        #pragma unroll
        for (int nt = 0; nt < 4; nt++) {
            size_t fo = (size_t)(((wave * 4 + nt) * 8 + it) * 64 + lane) * 8;
            bh[nt] = *(const bf16x8*)&W2fh[fo];
            bl[nt] = *(const bf16x8*)&W2fl[fo];
        }
        #pragma unroll
        for (int mt = 0; mt < 2; mt++) {
            int fb = ((mt * 8 + it) * 64 + lane) * 8;
            bf16x8 ah = *(bf16x8*)&sHf[fb];
            bf16x8 al = *(bf16x8*)&sLf[fb];
            #pragma unroll
            for (int nt = 0; nt < 4; nt++) {
                acc2[mt][nt] = __builtin_amdgcn_mfma_f32_16x16x32_bf16(ah, bh[nt], acc2[mt][nt], 0, 0, 0);
                acc2[mt][nt] = __builtin_amdgcn_mfma_f32_16x16x32_bf16(al, bh[nt], acc2[mt][nt], 0, 0, 0);
                acc2[mt][nt] = __builtin_amdgcn_mfma_f32_16x16x32_bf16(ah, bl[nt], acc2[mt][nt], 0, 0, 0);
            }
        }
    }
    // ---------- C-write (non-temporal): cols 0..127 -> C2a, 128..255 -> C2r ----------
    float* dstb = (wave < 2) ? C2a : C2r;
    int cb = (wave < 2) ? (wave * 64) : ((wave - 2) * 64);
    #pragma unroll
    for (int mt = 0; mt < 2; mt++)
        #pragma unroll
        for (int rg = 0; rg < 4; rg++) {
            int row = r0 + mt * 16 + quad * 4 + rg;
            #pragma unroll
            for (int nt = 0; nt < 4; nt++) {
                int col = cb + nt * 16 + l16;
                __builtin_nontemporal_store(acc2[mt][nt][rg], &dstb[(size_t)row * 128 + col]);
            }
        }
}

// ==== fused layer-2 tail: gather-mean p2 (C2a) + combine (C2r) + norm +
//      BOTH layer-3 per-node dots (q3 = W3l.h2, a3 = W3r.h2). h2 never
//      materialized. C2r is streamed once -> non-temporal load (keep L2
//      for the 6.4x-re-read C2a rows).

__global__ __launch_bounds__(256) void k_gather_combine(const float* __restrict__ C2a,
        const float* __restrict__ C2r,
        const int* __restrict__ rowptr, const int* __restrict__ csr,
        const float* __restrict__ b2, const float* __restrict__ W3l,
        const float* __restrict__ W3r,
        float* __restrict__ q3, float* __restrict__ a3) {
    __shared__ float sw[512];              // 0..255 = W3l, 256..511 = W3r
    int t = threadIdx.x;
    sw[t] = W3l[t];
    sw[256 + t] = W3r[t];
    __syncthreads();
    int tid = blockIdx.x * 256 + t;
    int node = tid >> 5;
    if (node >= NN) return;
    int l = tid & 31;
    int lane4 = l << 2;
    int beg = rowptr[node], end = rowptr[node + 1];
    f32x4 ac0 = {}, ac1 = {}, ac2 = {}, ac3 = {};
    int e = beg;
    for (; e + 3 < end; e += 4) {
        int s0 = csr[e], s1 = csr[e + 1], s2 = csr[e + 2], s3 = csr[e + 3];
        ac0 += *(const f32x4*)(C2a + (size_t)s0 * 128 + lane4);
        ac1 += *(const f32x4*)(C2a + (size_t)s1 * 128 + lane4);
        ac2 += *(const f32x4*)(C2a + (size_t)s2 * 128 + lane4);
        ac3 += *(const f32x4*)(C2a + (size_t)s3 * 128 + lane4);
    }
    if (e + 1 < end) {
        int s0 = csr[e], s1 = csr[e + 1];
        ac0 += *(const f32x4*)(C2a + (size_t)s0 * 128 + lane4);
        ac1 += *(const f32x4*)(C2a + (size_t)s1 * 128 + lane4);
        e += 2;
    }
    if (e < end) {
        ac2 += *(const f32x4*)(C2a + (size_t)csr[e] * 128 + lane4);
    }
    f32x4 acc = (ac0 + ac1) + (ac2 + ac3);
    float iv = 1.0f / (float)max(end - beg, 1);
    f32x4 r = __builtin_nontemporal_load((const f32x4*)&C2r[(size_t)node * 128 + lane4]);
    float4 b = *(const float4*)&b2[lane4];
    float v0 = acc[0] * iv + r[0] + b.x;
    float v1 = acc[1] * iv + r[1] + b.y;
    float v2 = acc[2] * iv + r[2] + b.z;
    float v3 = acc[3] * iv + r[3] + b.w;
    float s = v0 * v0 + v1 * v1 + v2 * v2 + v3 * v3;
    #pragma unroll
    for (int off = 16; off > 0; off >>= 1) s += __shfl_xor(s, off, 64);
    float invn = 1.0f / fmaxf(sqrtf(s), 1e-12f);
    float4 o;
    o.x = fmaxf(v0 * invn, 0.f); o.y = fmaxf(v1 * invn, 0.f);
    o.z = fmaxf(v2 * invn, 0.f); o.w = fmaxf(v3 * invn, 0.f);
    float q0 = o.x * sw[lane4] + o.y * sw[lane4+1] + o.z * sw[lane4+2] + o.w * sw[lane4+3];
    float q1 = o.x * sw[128+lane4] + o.y * sw[129+lane4] + o.z * sw[130+lane4] + o.w * sw[131+lane4];
    float c0 = o.x * sw[256+lane4] + o.y * sw[257+lane4] + o.z * sw[258+lane4] + o.w * sw[259+lane4];
    float c1 = o.x * sw[384+lane4] + o.y * sw[385+lane4] + o.z * sw[386+lane4] + o.w * sw[387+lane4];
    #pragma unroll
    for (int off = 16; off > 0; off >>= 1) {
        q0 += __shfl_xor(q0, off, 64);
        q1 += __shfl_xor(q1, off, 64);
        c0 += __shfl_xor(c0, off, 64);
        c1 += __shfl_xor(c1, off, 64);
    }
    if (l == 0) {
        q3[2 * node] = q0;
        q3[2 * node + 1] = q1;
        a3[2 * node] = c0;
        a3[2 * node + 1] = c1;
    }
}

// ============ final: tiny q3 gather + a3 + norm + log_softmax ============

__global__ __launch_bounds__(256) void k_final(const float* __restrict__ a3,
        const float* __restrict__ b3, const float* __restrict__ q3,
        const int* __restrict__ rowptr, const int* __restrict__ csr,
        float* __restrict__ out) {
    int i = blockIdx.x * 256 + threadIdx.x;
    if (i >= NN) return;
    int beg = rowptr[i], end = rowptr[i + 1];
    float g0 = 0.f, g1 = 0.f;
    for (int e = beg; e < end; e++) {
        int s = csr[e];
        g0 += q3[2 * s];
        g1 += q3[2 * s + 1];
    }
    float ivd = 1.0f / (float)max(end - beg, 1);
    float v0 = g0 * ivd + a3[2 * i] + b3[0];
    float v1 = g1 * ivd + a3[2 * i + 1] + b3[1];
    float invn = 1.0f / fmaxf(sqrtf(v0 * v0 + v1 * v1), 1e-12f);
    v0 *= invn; v1 *= invn;
    float mx = fmaxf(v0, v1);
    float l = logf(expf(v0 - mx) + expf(v1 - mx));
    out[2 * i] = v0 - mx - l;
    out[2 * i + 1] = v1 - mx - l;
}

// ================= launch =================

extern "C" void kernel_launch(void* const* d_in, const int* in_sizes, int n_in,
                              void* d_out, int out_size, void* d_ws, size_t ws_size,
                              hipStream_t stream) {
    const float* x   = (const float*)d_in[0];
    const int*   ei  = (const int*)d_in[1];
    const float* W1l = (const float*)d_in[2];
    const float* W1r = (const float*)d_in[3];
    const float* b1  = (const float*)d_in[4];
    const float* W2l = (const float*)d_in[5];
    const float* W2r = (const float*)d_in[6];
    const float* b2  = (const float*)d_in[7];
    const float* W3l = (const float*)d_in[8];
    const float* W3r = (const float*)d_in[9];
    const float* b3  = (const float*)d_in[10];
    float* out = (float*)d_out;
    const int* src = ei;
    const int* dst = ei + NE;

    // ---- workspace layout ----
    int* deg    = (int*)d_ws;                     // 102400
    int* rowptr = deg + 102400;
    int* cursor = rowptr + 102400;
    int* csr    = cursor + 102400;                // 655360
    int* bsum   = csr + 655360;                   // 128
    int* boff   = bsum + 128;                     // 128
    bf16_t* W1h  = (bf16_t*)(boff + 128);         // 65536 bf16 each (frag order)
    bf16_t* W1lo = W1h + 65536;
    bf16_t* W2h  = W1lo + 65536;
    bf16_t* W2lo = W2h + 65536;
    float* C2a  = (float*)(W2lo + 65536);         // NN*128 f32 (51.2MB, gathered)
    float* C2r  = C2a + (size_t)NN * 128;         // NN*128 f32 (own-row)
    float* q3   = C2r + (size_t)NN * 128;         // 200000
    float* a3   = q3 + 200000;                    // 200000

    // ---- CSR build (multi-block scan) ----
    hipMemsetAsync(deg, 0, NN * sizeof(int), stream);
    k_hist<<<(NE + 255) / 256, 256, 0, stream>>>(dst, deg);
    k_bsum<<<NBLK, 1024, 0, stream>>>(deg, bsum);
    k_bscan<<<1, 64, 0, stream>>>(bsum, boff, rowptr);
    k_scan2<<<NBLK, 1024, 0, stream>>>(deg, boff, rowptr, cursor);
    k_fill<<<(NE + 255) / 256, 256, 0, stream>>>(src, dst, cursor, csr);

    // ---- weight split (fragment order, both layers in one kernel) ----
    k_split_w<<<512, 256, 0, stream>>>(W1l, W1r, W2l, W2r, W1h, W1lo, W2h, W2lo);

    // ---- fused gather + layer-1 + layer-2 GEMM (h1 never leaves LDS) ----
    k_gemm_fused<<<GBLK, 256, 0, stream>>>(x, rowptr, csr, W1h, W1lo, W2h, W2lo, b1, C2a, C2r);

    // ---- layer-2 tail (gather+combine+q3+a3 fused; h2 eliminated) ----
    k_gather_combine<<<(NN * 32 + 255) / 256, 256, 0, stream>>>(C2a, C2r, rowptr, csr, b2, W3l, W3r, q3, a3);

    // ---- layer 3 (tiny q3 gather) ----
    k_final<<<(NN + 255) / 256, 256, 0, stream>>>(a3, b3, q3, rowptr, csr, out);
}